// Round 7
// baseline (102.482 us; speedup 1.0000x reference)
//
#include <hip/hip_runtime.h>

#define N_Q     40000
#define N_S     40000
#define KK      32
#define PP      15
#define IN_DIM  64
#define OUT_DIM 128

typedef __attribute__((ext_vector_type(8))) short short8;   // 8 bf16 (A/B frag)
typedef __attribute__((ext_vector_type(4))) float floatx4;  // mfma C/D frag

// float -> bf16 bits, round-to-nearest-even
static __device__ __forceinline__ short f2bf(float f) {
  union { float f; unsigned u; } v; v.f = f;
  unsigned r = v.u + 0x7FFFu + ((v.u >> 16) & 1u);
  return (short)(r >> 16);
}

// ws layout:
//   packed : (N_S+1) float4 @ 0      (sx,sy,sz,valid; last entry = shadow zeros)
//   wmf    : 240 KB @ 1 MiB          (W as bf16, pre-swizzled into mfma B-frags:
//            frag fi=(p*8+g)*2+kc holds B[n=lane&15][k=kc*32+quad*8+j] = W[p][k][g*16+n])

// Kernel 1: blocks [0,2500): rowsum -> valid flag + packed float4 point table.
//           blocks [2500,2740): swizzle W fp32 -> bf16 mfma B-fragment layout.
__global__ __launch_bounds__(256) void prep_kernel(
    const float* __restrict__ x, const float* __restrict__ s_pts,
    const float* __restrict__ weights,
    float4* __restrict__ packed, unsigned* __restrict__ wmf) {
  const int b = blockIdx.x;
  if (b < 2500) {
    const int t = b * 256 + threadIdx.x;
    const int row = t >> 4;   // 16 lanes per row
    const int sub = t & 15;
    float4 v = reinterpret_cast<const float4*>(x + (size_t)row * IN_DIM)[sub];
    float s = (v.x + v.y) + (v.z + v.w);
    s += __shfl_xor(s, 1, 64);
    s += __shfl_xor(s, 2, 64);
    s += __shfl_xor(s, 4, 64);
    s += __shfl_xor(s, 8, 64);
    if (sub == 0) {
      float4 pkt;
      pkt.x = s_pts[row * 3 + 0];
      pkt.y = s_pts[row * 3 + 1];
      pkt.z = s_pts[row * 3 + 2];
      pkt.w = (s > 0.0f) ? 1.0f : 0.0f;
      packed[row] = pkt;
    }
    if (t == 1) {   // shadow support point: origin, invalid
      float4 z; z.x = 0.f; z.y = 0.f; z.z = 0.f; z.w = 0.f;
      packed[N_S] = z;
    }
  } else {
    // one uint (2 bf16, consecutive k) per thread; flat index t matches
    // uint4 index fi*64+lane used by the consumer (t = fi*256 + lane*4 + j2)
    const int t = (b - 2500) * 256 + threadIdx.x;   // 0..61439
    const int j2   = t & 3;
    const int lane = (t >> 2) & 63;
    const int fi   = t >> 8;            // (p*8+g)*2+kc, 0..239
    const int kc = fi & 1, g = (fi >> 1) & 7, p = fi >> 4;
    const int c  = g * 16 + (lane & 15);
    const int k0 = kc * 32 + (lane >> 4) * 8 + 2 * j2;
    const float w0 = weights[(size_t)p * (IN_DIM * OUT_DIM) + (size_t)k0 * OUT_DIM + c];
    const float w1 = weights[(size_t)p * (IN_DIM * OUT_DIM) + (size_t)(k0 + 1) * OUT_DIM + c];
    wmf[t] = (unsigned)(unsigned short)f2bf(w0)
           | ((unsigned)(unsigned short)f2bf(w1) << 16);
  }
}

// Kernel 2 (fused): one WAVE owns 8 consecutive queries (4 iterations of the
// proven 2-queries-per-ballot scheme). Wave-fixed costs (kpts regs, R
// reduction, acc init, epilogue) amortize 4x vs R6. nidx prefetched for all
// iterations; divergent packed-gather software-pipelined one ahead. Hits run
// 16 MFMAs into rows m = 2e+(j>>5) of the shared accumulators.
__global__ __launch_bounds__(256, 4) void kpconv_fused_kernel(
    const float* __restrict__ q_pts, const int* __restrict__ nidx,
    const float* __restrict__ x, const float* __restrict__ kpts,
    const float4* __restrict__ packed, const uint4* __restrict__ wmf4,
    float* __restrict__ out) {
  const int lane = threadIdx.x & 63;
  const int wave = threadIdx.x >> 6;
  const int nW = (blockIdx.x * 4 + wave) * 8;   // wave's first query
  const size_t base = (size_t)nW * KK;

  // lane-resident kernel point (lanes >=15 duplicate point 0)
  const int pl = (lane < PP) ? lane : 0;
  const float kxl = kpts[pl * 3 + 0];
  const float kyl = kpts[pl * 3 + 1];
  const float kzl = kpts[pl * 3 + 2];

  // candidate radius: R = max_p |kp| + KP_EXTENT
  float r2m = kxl * kxl + kyl * kyl + kzl * kzl;
  #pragma unroll
  for (int s = 32; s; s >>= 1) r2m = fmaxf(r2m, __shfl_xor(r2m, s, 64));
  const float R  = sqrtf(r2m) + 0.05f;
  const float R2 = R * R;

  // prefetch all 4 neighbor-id vectors (coalesced) + query coords
  int ids[4];
  #pragma unroll
  for (int e = 0; e < 4; ++e) ids[e] = nidx[base + e * 64 + lane];
  float qxv[4], qyv[4], qzv[4];
  #pragma unroll
  for (int e = 0; e < 4; ++e) {
    const int n_e = nW + 2 * e + (lane >> 5);
    qxv[e] = q_pts[n_e * 3 + 0];
    qyv[e] = q_pts[n_e * 3 + 1];
    qzv[e] = q_pts[n_e * 3 + 2];
  }

  floatx4 acc[8];
  #pragma unroll
  for (int g = 0; g < 8; ++g) acc[g] = (floatx4){0.f, 0.f, 0.f, 0.f};

  float4 sp = packed[ids[0]];          // ONE divergent 16B gather / entry
  #pragma unroll
  for (int e = 0; e < 4; ++e) {
    float4 spn = (float4){0.f, 0.f, 0.f, 0.f};
    if (e < 3) spn = packed[ids[e + 1]];   // pipeline next gather
    const int id = ids[e];
    const bool real = (id < N_S);

    const float ox = sp.x - qxv[e];
    const float oy = sp.y - qyv[e];
    const float oz = sp.z - qzv[e];

    // neighbor_num for both queries of this iteration (shadow has sp.w==0)
    unsigned long long bal = __ballot(sp.w != 0.0f);
    int numA = __popc((unsigned)bal);          if (numA < 1) numA = 1;
    int numB = __popc((unsigned)(bal >> 32));  if (numB < 1) numB = 1;
    const float fnA = (float)numA, fnB = (float)numB;

    const float d2o = ox * ox + oy * oy + oz * oz;
    unsigned long long bc = __ballot(real && (d2o <= R2));
    while (bc) {
      const int j = (int)__ffsll(bc) - 1;
      bc &= bc - 1;
      const float oxj = __shfl(ox, j);
      const float oyj = __shfl(oy, j);
      const float ozj = __shfl(oz, j);
      // lanes 0-14 evaluate all 15 kernel points for this candidate
      const float dx = oxj - kxl, dy = oyj - kyl, dz = ozj - kzl;
      const float d2 = dx * dx + dy * dy + dz * dz;
      const bool hit = (lane < PP) && (d2 < 0.0025f);
      unsigned long long bh = __ballot(hit);
      if (bh == 0ull) continue;                 // ~85% of candidates exit here

      const float wcb = hit ? (1.0f - 20.0f * sqrtf(d2)) : 0.0f;
      const int   idj = __shfl(id, j);
      const float inj = 1.0f / ((j < 32) ? fnA : fnB);
      const int   m   = 2 * e + (j >> 5);       // acc row for this query
      while (bh) {
        const int p = (int)__ffsll(bh) - 1;
        bh &= bh - 1;
        const float wj = __shfl(wcb, p) * inj;
        // A fragments: row m only. A[m][k=quad*8+i] = wj * x[idj][k]
        short8 af0 = {0, 0, 0, 0, 0, 0, 0, 0};
        short8 af1 = {0, 0, 0, 0, 0, 0, 0, 0};
        if ((lane & 15) == m) {
          const float4* xr = reinterpret_cast<const float4*>(x + (size_t)idj * IN_DIM);
          const int q4 = (lane >> 4) * 2;
          const float4 xa = xr[q4],     xb = xr[q4 + 1];   // k 0..31
          const float4 xc = xr[q4 + 8], xd = xr[q4 + 9];   // k 32..63
          af0[0] = f2bf(wj * xa.x); af0[1] = f2bf(wj * xa.y);
          af0[2] = f2bf(wj * xa.z); af0[3] = f2bf(wj * xa.w);
          af0[4] = f2bf(wj * xb.x); af0[5] = f2bf(wj * xb.y);
          af0[6] = f2bf(wj * xb.z); af0[7] = f2bf(wj * xb.w);
          af1[0] = f2bf(wj * xc.x); af1[1] = f2bf(wj * xc.y);
          af1[2] = f2bf(wj * xc.z); af1[3] = f2bf(wj * xc.w);
          af1[4] = f2bf(wj * xd.x); af1[5] = f2bf(wj * xd.y);
          af1[6] = f2bf(wj * xd.z); af1[7] = f2bf(wj * xd.w);
        }
        #pragma unroll
        for (int g = 0; g < 8; ++g) {
          const uint4 b0 = wmf4[(size_t)((p * 8 + g) * 2 + 0) * 64 + lane];
          acc[g] = __builtin_amdgcn_mfma_f32_16x16x32_bf16(
              af0, __builtin_bit_cast(short8, b0), acc[g], 0, 0, 0);
          const uint4 b1 = wmf4[(size_t)((p * 8 + g) * 2 + 1) * 64 + lane];
          acc[g] = __builtin_amdgcn_mfma_f32_16x16x32_bf16(
              af1, __builtin_bit_cast(short8, b1), acc[g], 0, 0, 0);
        }
      }
    }
    sp = spn;
  }

  // Epilogue: D row = (lane>>4)*4 + reg, col = lane&15. Rows 0-7 are this
  // wave's 8 queries -> lanes 0-31 hold them. Zero-hit queries write zeros.
  if (lane < 32) {
    const int col = lane & 15;
    const int rb  = (lane >> 4) * 4;   // 0 or 4
    #pragma unroll
    for (int r = 0; r < 4; ++r) {
      #pragma unroll
      for (int g = 0; g < 8; ++g) {
        out[(size_t)(nW + rb + r) * OUT_DIM + g * 16 + col] = acc[g][r];
      }
    }
  }
}

extern "C" void kernel_launch(void* const* d_in, const int* in_sizes, int n_in,
                              void* d_out, int out_size, void* d_ws, size_t ws_size,
                              hipStream_t stream) {
  const float* q_pts   = (const float*)d_in[0];
  const float* s_pts   = (const float*)d_in[1];
  const int*   nidx    = (const int*)d_in[2];
  const float* x       = (const float*)d_in[3];
  const float* weights = (const float*)d_in[4];
  const float* kpts    = (const float*)d_in[5];
  float* out = (float*)d_out;

  char* ws = (char*)d_ws;
  float4*   packed = (float4*)ws;                     // (N_S+1)*16 B = 640 KB
  unsigned* wmf    = (unsigned*)(ws + (1u << 20));    // 240 KB, mfma B-frag order

  prep_kernel<<<2740, 256, 0, stream>>>(x, s_pts, weights, packed, wmf);
  // 8 queries per wave, 4 waves per block -> 32 queries per block
  kpconv_fused_kernel<<<N_Q / 32, 256, 0, stream>>>(
      q_pts, nidx, x, kpts, packed, (const uint4*)wmf, out);
}

// Round 8
// 100.436 us; speedup vs baseline: 1.0204x; 1.0204x over previous
//
#include <hip/hip_runtime.h>

#define N_Q     40000
#define N_S     40000
#define KK      32
#define PP      15
#define IN_DIM  64
#define OUT_DIM 128

typedef __attribute__((ext_vector_type(8))) short short8;   // 8 bf16 (A/B frag)
typedef __attribute__((ext_vector_type(4))) float floatx4;  // mfma C/D frag

// float -> bf16 bits, round-to-nearest-even
static __device__ __forceinline__ short f2bf(float f) {
  union { float f; unsigned u; } v; v.f = f;
  unsigned r = v.u + 0x7FFFu + ((v.u >> 16) & 1u);
  return (short)(r >> 16);
}

// ws layout:
//   packed : (N_S+1) float4 @ 0       (sx,sy,sz,valid; last entry = shadow zeros)
//   wmf    : 240 KB @ 1 MiB           (W bf16, pre-swizzled mfma B-frags)
//   kpt4   : 16 float4 @ 1.5 MiB      (kpt4[p]=(kx,ky,kz,0), p<15; kpt4[15].x=R2)

// Kernel 1: blocks [0,2500): rowsum -> valid flag + packed float4 point table.
//           blocks [2500,2740): swizzle W fp32 -> bf16 mfma B-fragment layout;
//           first threads also build the kpt4 table and R2.
__global__ __launch_bounds__(256) void prep_kernel(
    const float* __restrict__ x, const float* __restrict__ s_pts,
    const float* __restrict__ weights, const float* __restrict__ kpts,
    float4* __restrict__ packed, unsigned* __restrict__ wmf,
    float4* __restrict__ kpt4) {
  const int b = blockIdx.x;
  if (b < 2500) {
    const int t = b * 256 + threadIdx.x;
    const int row = t >> 4;   // 16 lanes per row
    const int sub = t & 15;
    float4 v = reinterpret_cast<const float4*>(x + (size_t)row * IN_DIM)[sub];
    float s = (v.x + v.y) + (v.z + v.w);
    s += __shfl_xor(s, 1, 64);
    s += __shfl_xor(s, 2, 64);
    s += __shfl_xor(s, 4, 64);
    s += __shfl_xor(s, 8, 64);
    if (sub == 0) {
      float4 pkt;
      pkt.x = s_pts[row * 3 + 0];
      pkt.y = s_pts[row * 3 + 1];
      pkt.z = s_pts[row * 3 + 2];
      pkt.w = (s > 0.0f) ? 1.0f : 0.0f;
      packed[row] = pkt;
    }
    if (t == 1) {   // shadow support point: origin, invalid
      float4 z; z.x = 0.f; z.y = 0.f; z.z = 0.f; z.w = 0.f;
      packed[N_S] = z;
    }
  } else {
    // one uint (2 bf16, consecutive k) per thread; flat index t matches
    // uint4 index fi*64+lane used by the consumer (t = fi*256 + lane*4 + j2)
    const int t = (b - 2500) * 256 + threadIdx.x;   // 0..61439
    if (t < PP) {
      float4 kp;
      kp.x = kpts[t * 3 + 0];
      kp.y = kpts[t * 3 + 1];
      kp.z = kpts[t * 3 + 2];
      kp.w = 0.f;
      kpt4[t] = kp;
    } else if (t == PP) {   // R2 = (max_p |kp| + 0.05)^2
      float m2 = 0.f;
      for (int p = 0; p < PP; ++p) {
        const float a = kpts[p * 3 + 0], bb = kpts[p * 3 + 1], c = kpts[p * 3 + 2];
        m2 = fmaxf(m2, a * a + bb * bb + c * c);
      }
      const float R = sqrtf(m2) + 0.05f;
      float4 rr; rr.x = R * R; rr.y = 0.f; rr.z = 0.f; rr.w = 0.f;
      kpt4[PP] = rr;
    }
    const int j2   = t & 3;
    const int lane = (t >> 2) & 63;
    const int fi   = t >> 8;            // (p*8+g)*2+kc, 0..239
    const int kc = fi & 1, g = (fi >> 1) & 7, p = fi >> 4;
    const int c  = g * 16 + (lane & 15);
    const int k0 = kc * 32 + (lane >> 4) * 8 + 2 * j2;
    const float w0 = weights[(size_t)p * (IN_DIM * OUT_DIM) + (size_t)k0 * OUT_DIM + c];
    const float w1 = weights[(size_t)p * (IN_DIM * OUT_DIM) + (size_t)(k0 + 1) * OUT_DIM + c];
    wmf[t] = (unsigned)(unsigned short)f2bf(w0)
           | ((unsigned)(unsigned short)f2bf(w1) << 16);
  }
}

// Kernel 2 (fused): one thread per (query, neighbor); lanes 0-31 = query A,
// 32-63 = query B (R6 structure, best measured). Cuts vs R6: R2 precomputed
// (no per-wave shfl-max reduction), kernel points via one 16B table load,
// zero-candidate early exit, lazy acc init, single-float4 zero epilogue for
// no-hit waves, hit-only shfls deferred under the hit branch.
__global__ __launch_bounds__(256, 4) void kpconv_fused_kernel(
    const float* __restrict__ q_pts, const int* __restrict__ nidx,
    const float* __restrict__ x, const float4* __restrict__ packed,
    const uint4* __restrict__ wmf4, const float4* __restrict__ kpt4,
    float* __restrict__ out) {
  const int tid  = blockIdx.x * 256 + threadIdx.x;
  const int lane = threadIdx.x & 63;
  const int n  = tid >> 5;            // this lane's query
  const int nA = (tid & ~63) >> 5;    // wave's first query

  const int id = nidx[tid];           // coalesced; id in [0, N_S]

  // lane-resident kernel point via table (lanes >=15 duplicate point 0)
  const float4 kp = kpt4[(lane < PP) ? lane : 0];
  const float R2 = kpt4[PP].x;        // uniform broadcast load

  const float4 sp = packed[id];       // ONE divergent 16B gather
  const bool real = (id < N_S);

  const float ox = sp.x - q_pts[n * 3 + 0];
  const float oy = sp.y - q_pts[n * 3 + 1];
  const float oz = sp.z - q_pts[n * 3 + 2];

  // neighbor_num for both queries (shadow entry has sp.w == 0)
  unsigned long long bal = __ballot(sp.w != 0.0f);
  int numA = __popc((unsigned)bal);          if (numA < 1) numA = 1;
  int numB = __popc((unsigned)(bal >> 32));  if (numB < 1) numB = 1;
  const float fnA = (float)numA, fnB = (float)numB;

  const float d2o = ox * ox + oy * oy + oz * oz;
  unsigned long long bc = __ballot(real && (d2o <= R2));

  if (bc == 0ull) {   // ~9% of waves: no candidate at all -> zero rows, done
    float4 z; z.x = 0.f; z.y = 0.f; z.z = 0.f; z.w = 0.f;
    reinterpret_cast<float4*>(out + (size_t)nA * OUT_DIM)[lane] = z;  // 2 rows
    return;
  }

  floatx4 acc[8];
  bool inited = false;

  while (bc) {
    const int j = (int)__ffsll(bc) - 1;
    bc &= bc - 1;
    const float oxj = __shfl(ox, j);
    const float oyj = __shfl(oy, j);
    const float ozj = __shfl(oz, j);
    // lanes 0-14 evaluate all 15 kernel points for this candidate
    const float dx = oxj - kp.x, dy = oyj - kp.y, dz = ozj - kp.z;
    const float d2 = dx * dx + dy * dy + dz * dz;
    const bool hit = (lane < PP) && (d2 < 0.0025f);
    unsigned long long bh = __ballot(hit);
    if (bh == 0ull) continue;                 // ~85% of candidates exit here

    const float wcb = hit ? (1.0f - 20.0f * sqrtf(d2)) : 0.0f;
    const int   idj = __shfl(id, j);
    const float inj = 1.0f / ((j < 32) ? fnA : fnB);
    const int   m   = j >> 5;                 // acc row: 0 = query A, 1 = B
    while (bh) {
      const int p = (int)__ffsll(bh) - 1;
      bh &= bh - 1;
      const float wj = __shfl(wcb, p) * inj;
      if (!inited) {                          // lazy: only hit-waves pay init
        #pragma unroll
        for (int g = 0; g < 8; ++g) acc[g] = (floatx4){0.f, 0.f, 0.f, 0.f};
        inited = true;
      }
      // A fragments: row m only. A[m][k=quad*8+i] = wj * x[idj][k]
      short8 af0 = {0, 0, 0, 0, 0, 0, 0, 0};
      short8 af1 = {0, 0, 0, 0, 0, 0, 0, 0};
      if ((lane & 15) == m) {
        const float4* xr = reinterpret_cast<const float4*>(x + (size_t)idj * IN_DIM);
        const int q4 = (lane >> 4) * 2;
        const float4 xa = xr[q4],     xb = xr[q4 + 1];   // k 0..31
        const float4 xc = xr[q4 + 8], xd = xr[q4 + 9];   // k 32..63
        af0[0] = f2bf(wj * xa.x); af0[1] = f2bf(wj * xa.y);
        af0[2] = f2bf(wj * xa.z); af0[3] = f2bf(wj * xa.w);
        af0[4] = f2bf(wj * xb.x); af0[5] = f2bf(wj * xb.y);
        af0[6] = f2bf(wj * xb.z); af0[7] = f2bf(wj * xb.w);
        af1[0] = f2bf(wj * xc.x); af1[1] = f2bf(wj * xc.y);
        af1[2] = f2bf(wj * xc.z); af1[3] = f2bf(wj * xc.w);
        af1[4] = f2bf(wj * xd.x); af1[5] = f2bf(wj * xd.y);
        af1[6] = f2bf(wj * xd.z); af1[7] = f2bf(wj * xd.w);
      }
      #pragma unroll
      for (int g = 0; g < 8; ++g) {
        const uint4 b0 = wmf4[(size_t)((p * 8 + g) * 2 + 0) * 64 + lane];
        acc[g] = __builtin_amdgcn_mfma_f32_16x16x32_bf16(
            af0, __builtin_bit_cast(short8, b0), acc[g], 0, 0, 0);
        const uint4 b1 = wmf4[(size_t)((p * 8 + g) * 2 + 1) * 64 + lane];
        acc[g] = __builtin_amdgcn_mfma_f32_16x16x32_bf16(
            af1, __builtin_bit_cast(short8, b1), acc[g], 0, 0, 0);
      }
    }
  }

  if (!inited) {      // candidates but no hit (~60% of waves): zero rows
    float4 z; z.x = 0.f; z.y = 0.f; z.z = 0.f; z.w = 0.f;
    reinterpret_cast<float4*>(out + (size_t)nA * OUT_DIM)[lane] = z;
    return;
  }

  // D layout: col = lane&15, row = (lane>>4)*4 + reg -> rows 0/1 in lanes
  // 0-15, regs 0/1.
  if (lane < 16) {
    #pragma unroll
    for (int g = 0; g < 8; ++g) {
      out[(size_t)nA * OUT_DIM + g * 16 + lane]       = acc[g][0];
      out[(size_t)(nA + 1) * OUT_DIM + g * 16 + lane] = acc[g][1];
    }
  }
}

extern "C" void kernel_launch(void* const* d_in, const int* in_sizes, int n_in,
                              void* d_out, int out_size, void* d_ws, size_t ws_size,
                              hipStream_t stream) {
  const float* q_pts   = (const float*)d_in[0];
  const float* s_pts   = (const float*)d_in[1];
  const int*   nidx    = (const int*)d_in[2];
  const float* x       = (const float*)d_in[3];
  const float* weights = (const float*)d_in[4];
  const float* kpts    = (const float*)d_in[5];
  float* out = (float*)d_out;

  char* ws = (char*)d_ws;
  float4*   packed = (float4*)ws;                      // (N_S+1)*16 B = 640 KB
  unsigned* wmf    = (unsigned*)(ws + (1u << 20));     // 240 KB, B-frag order
  float4*   kpt4   = (float4*)(ws + (3u << 19));       // 1.5 MiB: 16 float4

  prep_kernel<<<2740, 256, 0, stream>>>(x, s_pts, weights, kpts,
                                        packed, wmf, kpt4);
  kpconv_fused_kernel<<<(N_Q * KK) / 256, 256, 0, stream>>>(
      q_pts, nidx, x, packed, (const uint4*)wmf, kpt4, out);
}